// Round 12
// baseline (305.783 us; speedup 1.0000x reference)
//
#include <hip/hip_runtime.h>

#define N_NODE 100000
#define EMB 112
#define EMBP 128                      // padded bf16 row: 256 B, line-aligned
#define BATCH 512
#define SEQL 50
#define NNZ 1600000
#define NROWS (BATCH * SEQL)

#define BROWS 256                     // rows per bucket
#define NBUCK ((N_NODE + BROWS - 1) / BROWS)      // 391
#define BUCK_CAP 4608                 // mean 4096, sd 64 -> 8 sigma headroom
#define TILE_E 6250                   // 256 bin blocks x 1024 threads, exact
#define P1_BLOCKS 256
#define NPREP1024 (N_NODE * 32 / 1024)            // 3125 prep blocks @1024 thr
#define NGEMM 64                      // 64x64-tile DA gemm blocks

typedef _Float16 half2_t __attribute__((ext_vector_type(2)));

__device__ __forceinline__ float bf2f(unsigned short u) {
    return __uint_as_float((unsigned)u << 16);
}
__device__ __forceinline__ unsigned short f2bf(float f) {
    unsigned u = __float_as_uint(f);
    return (unsigned short)((u + 0x7FFF + ((u >> 16) & 1)) >> 16);   // RNE
}
__device__ __forceinline__ float fdot2(half2_t a, half2_t b, float c) {
#if defined(__has_builtin)
#if __has_builtin(__builtin_amdgcn_fdot2)
    return __builtin_amdgcn_fdot2(a, b, c, false);
#else
    return c + (float)a[0] * (float)b[0] + (float)a[1] * (float)b[1];
#endif
#else
    return c + (float)a[0] * (float)b[0] + (float)a[1] * (float)b[1];
#endif
}

// ---- fused: edge binning (blocks [0,256), head of grid) + prep behind -----
// Bin branch: block-local counting sort in LDS so staged[] writes are
// line-coalesced. rows[] register-staged across passes (read once).
struct BinSmem {
    uint2 sdata[TILE_E];              // 50000 B, bucket-grouped edges
    unsigned short sbuck[TILE_E];     // 12500 B, bucket id per slot
    int hist[NBUCK];
    int sc[NBUCK];                    // inclusive scan
    int gbase[NBUCK];                 // global reservation base
    int cur[NBUCK];                   // local scatter cursor
};

__global__ __launch_bounds__(1024) void prep_bin(
    const float* __restrict__ in, unsigned short* __restrict__ out,
    const int* __restrict__ rows, const int* __restrict__ cols,
    const float* __restrict__ vals,
    int* __restrict__ bcur, uint2* __restrict__ staged)
{
    __shared__ BinSmem sm;
    const int t = threadIdx.x;

    if (blockIdx.x >= P1_BLOCKS) {
        // ---- prep branch: fp32 -> padded bf16 table ----
        int i = (blockIdx.x - P1_BLOCKS) * 1024 + t;
        int r = i >> 5, c = i & 31;
        ushort4 o; o.x = 0; o.y = 0; o.z = 0; o.w = 0;
        if (c < 28) {
            float4 v = ((const float4*)in)[r * 28 + c];
            o.x = f2bf(v.x); o.y = f2bf(v.y); o.z = f2bf(v.z); o.w = f2bf(v.w);
        }
        ((ushort4*)out)[i] = o;
        return;
    }

    // ---- edge_bin branch ----
    const int e0 = blockIdx.x * TILE_E;

    // A: histogram, register-staging rows (max 7 edges per thread)
    int rreg[7];
    int nume = 0;
    for (int i = t; i < NBUCK; i += 1024) sm.hist[i] = 0;
    __syncthreads();
    #pragma unroll
    for (int j = 0; j < 7; ++j) {
        int e = e0 + t + j * 1024;
        if (t + j * 1024 < TILE_E) {
            int r = rows[e];
            rreg[j] = r;
            atomicAdd(&sm.hist[r >> 8], 1);
            nume = j + 1;
        }
    }
    __syncthreads();

    // B: local exclusive scan + global reservation
    for (int i = t; i < NBUCK; i += 1024) sm.sc[i] = sm.hist[i];
    __syncthreads();
    for (int o = 1; o < NBUCK; o <<= 1) {
        int v = 0;
        if (t < NBUCK && t >= o) v = sm.sc[t - o];
        __syncthreads();
        if (t < NBUCK) sm.sc[t] += v;
        __syncthreads();
    }
    if (t < NBUCK) {
        int c = sm.hist[t];
        int excl = sm.sc[t] - c;
        sm.cur[t] = excl;
        sm.gbase[t] = (c > 0) ? atomicAdd(&bcur[t], c) : 0;
    }
    __syncthreads();

    // C: scatter edges into LDS grouped by bucket (rows from registers)
    #pragma unroll
    for (int j = 0; j < 7; ++j) {
        if (j < nume) {
            int e = e0 + t + j * 1024;
            int r = rreg[j];
            int b = r >> 8;
            int k = atomicAdd(&sm.cur[b], 1);
            uint2 s;
            s.x = ((unsigned)(r & 255) << 24) | (unsigned)cols[e];
            s.y = __float_as_uint(vals[e]);
            sm.sdata[k] = s;
            sm.sbuck[k] = (unsigned short)b;
        }
    }
    __syncthreads();

    // D: line-coalesced write-out (consecutive slots -> consecutive gdst)
    for (int i = t; i < TILE_E; i += 1024) {
        int b = sm.sbuck[i];
        int lbase = sm.sc[b] - sm.hist[b];
        staged[(size_t)b * BUCK_CAP + sm.gbase[b] + (i - lbase)] = sm.sdata[i];
    }
}

// ---- fused: bucket sort/csr/spmm (blocks [0,391)) + DA gemm ([391,455)) ---
// Gather uses a 12-deep load batch to raise per-wave memory parallelism;
// launch_bounds(1024,8) pins VGPR<=64 so 2 blocks/CU residency holds.
struct SortSmem {
    uint2 s_sorted[BUCK_CAP];
    int cnt[BROWS];
    int sc[BROWS];
    int cur[BROWS];
};
struct Gemm64Smem {
    float sD[64][33];
    float sA[32][65];
};
union BuckSmem { SortSmem s; Gemm64Smem g; };

__global__ __launch_bounds__(1024, 8) void bucket_csr_spmm(
    const uint2* __restrict__ staged, const int* __restrict__ bcur,
    const unsigned short* __restrict__ src, unsigned short* __restrict__ dst,
    int2* __restrict__ csr_cv, int* __restrict__ row_start,
    int* __restrict__ counts,
    const float* __restrict__ D, const float* __restrict__ A,
    float* __restrict__ DA)
{
    __shared__ BuckSmem sm;
    const int t = threadIdx.x;

    if (blockIdx.x >= NBUCK) {
        // ---------------- DA = D @ A, 64x64 tile per block ----------------
        const int bid = blockIdx.x - NBUCK;
        const int i0 = (bid >> 3) * 64;
        const int j0 = (bid & 7) * 64;
        const int tx = t & 31;
        const int ty = t >> 5;
        float a00 = 0.f, a01 = 0.f, a10 = 0.f, a11 = 0.f;
        for (int k0 = 0; k0 < BATCH; k0 += 32) {
            int idx = t;
            #pragma unroll
            for (int rpt = 0; rpt < 2; ++rpt, idx += 1024) {
                int r = idx >> 5, c = idx & 31;
                sm.g.sD[r][c] = D[(i0 + r) * BATCH + k0 + c];
                int r2 = idx >> 6, c2 = idx & 63;
                sm.g.sA[r2][c2] = A[(k0 + r2) * BATCH + j0 + c2];
            }
            __syncthreads();
            #pragma unroll 8
            for (int kk = 0; kk < 32; ++kk) {
                float d0 = sm.g.sD[2 * ty][kk], d1 = sm.g.sD[2 * ty + 1][kk];
                float b0 = sm.g.sA[kk][2 * tx], b1 = sm.g.sA[kk][2 * tx + 1];
                a00 += d0 * b0; a01 += d0 * b1;
                a10 += d1 * b0; a11 += d1 * b1;
            }
            __syncthreads();
        }
        DA[(i0 + 2 * ty) * BATCH + j0 + 2 * tx] = a00;
        DA[(i0 + 2 * ty) * BATCH + j0 + 2 * tx + 1] = a01;
        DA[(i0 + 2 * ty + 1) * BATCH + j0 + 2 * tx] = a10;
        DA[(i0 + 2 * ty + 1) * BATCH + j0 + 2 * tx + 1] = a11;
        return;
    }

    // ---------------- bucket sort + csr emit + spmm layer 1 ----------------
    const int b = blockIdx.x;
    const int n = bcur[b];
    const size_t base = (size_t)b * BUCK_CAP;
    const int r0 = b << 8;

    if (t < BROWS) sm.s.cnt[t] = 0;
    __syncthreads();
    for (int i = t; i < n; i += 1024)
        atomicAdd(&sm.s.cnt[staged[base + i].x >> 24], 1);
    __syncthreads();

    if (t < BROWS) sm.s.sc[t] = sm.s.cnt[t];
    __syncthreads();
    for (int o = 1; o < BROWS; o <<= 1) {
        int v = 0;
        if (t < BROWS && t >= o) v = sm.s.sc[t - o];
        __syncthreads();
        if (t < BROWS) sm.s.sc[t] += v;
        __syncthreads();
    }
    if (t < BROWS) {
        int excl = sm.s.sc[t] - sm.s.cnt[t];
        sm.s.cur[t] = excl;
        int row = r0 + t;
        if (row < N_NODE) {
            row_start[row] = (int)base + excl;
            counts[row] = sm.s.cnt[t];
        }
    }
    __syncthreads();

    for (int i = t; i < n; i += 1024) {
        uint2 s = staged[base + i];
        int rl = s.x >> 24;
        int k = atomicAdd(&sm.s.cur[rl], 1);
        uint2 e;
        e.x = s.x & 0x00FFFFFFu;
        e.y = s.y;
        sm.s.s_sorted[k] = e;
    }
    __syncthreads();

    for (int i = t; i < n; i += 1024) {
        uint2 e = sm.s.s_sorted[i];
        int2 cv; cv.x = (int)e.x; cv.y = (int)e.y;
        csr_cv[base + i] = cv;
    }

    // spmm layer 1 for this bucket's 256 rows, edges from LDS
    const int wave = t >> 6;
    const int lane = t & 63;
    const int half = lane >> 5;
    const int hl = lane & 31;
    const int d0 = hl * 4;

    for (int it = 0; it < 8; ++it) {
        int rl = wave * 16 + it * 2 + half;
        int row = r0 + rl;
        bool valid = row < N_NODE;
        int n_r = valid ? sm.s.cnt[rl] : 0;
        int beg = valid ? (sm.s.sc[rl] - sm.s.cnt[rl]) : 0;

        float a0 = 0.f, a1 = 0.f, a2 = 0.f, a3 = 0.f;
        int i = 0;
        for (; i + 12 <= n_r; i += 12) {
            ushort4 u[12];
            #pragma unroll
            for (int j = 0; j < 12; ++j) {
                unsigned cx = sm.s.s_sorted[beg + i + j].x;
                u[j] = *(const ushort4*)(src + (size_t)cx * EMBP + d0);
            }
            #pragma unroll
            for (int j = 0; j < 12; ++j) {
                float v = __uint_as_float(sm.s.s_sorted[beg + i + j].y);
                a0 += v * bf2f(u[j].x);
                a1 += v * bf2f(u[j].y);
                a2 += v * bf2f(u[j].z);
                a3 += v * bf2f(u[j].w);
            }
        }
        for (; i + 4 <= n_r; i += 4) {
            ushort4 u[4];
            #pragma unroll
            for (int j = 0; j < 4; ++j) {
                unsigned cx = sm.s.s_sorted[beg + i + j].x;
                u[j] = *(const ushort4*)(src + (size_t)cx * EMBP + d0);
            }
            #pragma unroll
            for (int j = 0; j < 4; ++j) {
                float v = __uint_as_float(sm.s.s_sorted[beg + i + j].y);
                a0 += v * bf2f(u[j].x);
                a1 += v * bf2f(u[j].y);
                a2 += v * bf2f(u[j].z);
                a3 += v * bf2f(u[j].w);
            }
        }
        for (; i < n_r; ++i) {
            uint2 e = sm.s.s_sorted[beg + i];
            float v = __uint_as_float(e.y);
            ushort4 u = *(const ushort4*)(src + (size_t)e.x * EMBP + d0);
            a0 += v * bf2f(u.x);
            a1 += v * bf2f(u.y);
            a2 += v * bf2f(u.z);
            a3 += v * bf2f(u.w);
        }
        if (valid) {
            ushort4 o;
            o.x = f2bf(a0); o.y = f2bf(a1); o.z = f2bf(a2); o.w = f2bf(a3);
            *(ushort4*)(dst + (size_t)row * EMBP + d0) = o;
        }
    }
}

// ---- gather_seq: on-the-fly layer-2 rows for all (b,l) slots --------------
__global__ __launch_bounds__(256, 8) void gather_seq(
    const float* __restrict__ emb0,
    const unsigned short* __restrict__ e1b,
    const int2* __restrict__ csr_cv, const int* __restrict__ row_start,
    const int* __restrict__ counts,
    const int* __restrict__ items,
    float* __restrict__ seqg)
{
    const int t = threadIdx.x;
    const int hw = t >> 5;        // 0..7 half-waves
    const int hl = t & 31;
    const int d0 = hl * 4;
    const int slot = blockIdx.x * 8 + hw;
    if (slot >= NROWS) return;

    float a0 = 0.f, a1 = 0.f, a2 = 0.f, a3 = 0.f;
    const int g = items[slot];
    if (g > 0) {
        const int r = g - 1;
        const int n = counts[r];
        const int beg = row_start[r];
        int i = 0;
        for (; i + 12 <= n; i += 12) {
            ushort4 u[12];
            #pragma unroll
            for (int j = 0; j < 12; ++j) {
                int2 cv = csr_cv[beg + i + j];
                u[j] = *(const ushort4*)(e1b + (size_t)cv.x * EMBP + d0);
            }
            #pragma unroll
            for (int j = 0; j < 12; ++j) {
                float v = __int_as_float(csr_cv[beg + i + j].y);
                a0 += v * bf2f(u[j].x);
                a1 += v * bf2f(u[j].y);
                a2 += v * bf2f(u[j].z);
                a3 += v * bf2f(u[j].w);
            }
        }
        for (; i + 4 <= n; i += 4) {
            ushort4 u[4];
            #pragma unroll
            for (int j = 0; j < 4; ++j) {
                int2 cv = csr_cv[beg + i + j];
                u[j] = *(const ushort4*)(e1b + (size_t)cv.x * EMBP + d0);
            }
            #pragma unroll
            for (int j = 0; j < 4; ++j) {
                float v = __int_as_float(csr_cv[beg + i + j].y);
                a0 += v * bf2f(u[j].x);
                a1 += v * bf2f(u[j].y);
                a2 += v * bf2f(u[j].z);
                a3 += v * bf2f(u[j].w);
            }
        }
        for (; i < n; ++i) {
            int2 cv = csr_cv[beg + i];
            float v = __int_as_float(cv.y);
            ushort4 u = *(const ushort4*)(e1b + (size_t)cv.x * EMBP + d0);
            a0 += v * bf2f(u.x);
            a1 += v * bf2f(u.y);
            a2 += v * bf2f(u.z);
            a3 += v * bf2f(u.w);
        }
        // + emb1 self + emb0 self
        ushort4 u1 = *(const ushort4*)(e1b + (size_t)r * EMBP + d0);
        a0 += bf2f(u1.x); a1 += bf2f(u1.y); a2 += bf2f(u1.z); a3 += bf2f(u1.w);
        if (hl < 28) {
            float4 v0 = *(const float4*)(emb0 + (size_t)r * EMB + d0);
            a0 += v0.x; a1 += v0.y; a2 += v0.z; a3 += v0.w;
        }
        a0 *= (1.f / 3.f); a1 *= (1.f / 3.f);
        a2 *= (1.f / 3.f); a3 *= (1.f / 3.f);
    }
    if (hl < 28) {
        float4 w; w.x = a0; w.y = a1; w.z = a2; w.w = a3;
        *(float4*)(seqg + (size_t)slot * EMB + d0) = w;
    }
}

// ---------------- attention (slen-capped), 512 pure-attn blocks ------------
// LDS ~48 KB (fp16 Q/K) -> 3 blocks/CU. mask is a contiguous prefix
// (arange(SEQ) < session_len), so capping loops at slen is bit-identical.
#define APAD 116
#define HPAD 120
struct AttnSmem {
    float s_seq[52][APAD];            // 23.6 KB
    _Float16 sQ[SEQL][HPAD];          // 11.7 KB
    _Float16 sK[SEQL][HPAD];          // 11.7 KB
    float s_part[SEQL][4];
    float s_beta[SEQL];
};

__global__ __launch_bounds__(256, 3) void attn_pool(
    const float* __restrict__ seqg,
    const float* __restrict__ Wq, const float* __restrict__ Wk,
    const int* __restrict__ session_len,
    float* __restrict__ seq_h, float* __restrict__ acc2)
{
    __shared__ AttnSmem sm;
    const int t = threadIdx.x;
    const int b = blockIdx.x;
    const int slen_i = session_len[b];            // uniform per block

    // phase 1: coalesced stage of precomputed seq rows
    for (int u = t; u < SEQL * 28; u += 256) {
        int l = u / 28;
        int q = u - l * 28;
        *(float4*)&sm.s_seq[l][q * 4] =
            *(const float4*)(seqg + (size_t)(b * SEQL + l) * EMB + q * 4);
    }
    if (t < 2 * 28) {                 // zero pad rows 50,51
        int l = SEQL + (t / 28);
        int q = t - (t / 28) * 28;
        float4 z; z.x = 0.f; z.y = 0.f; z.z = 0.f; z.w = 0.f;
        *(float4*)&sm.s_seq[l][q * 4] = z;
    }
    __syncthreads();

    // phase 2: Q/K projection, only rows < slen (rest are exact zeros
    // downstream). rgmax*28 work items, 4x4 register tiles.
    const int rgmax = (slen_i + 3) >> 2;
    for (int u = t; u < rgmax * 28; u += 256) {
        const int rg = u / 28;
        const int e0 = (u - rg * 28) * 4;
        float accq[4][4] = {{0.f}}, acck[4][4] = {{0.f}};
        #pragma unroll 2
        for (int d4 = 0; d4 < 28; ++d4) {
            float sa[4][4];
            #pragma unroll
            for (int rr = 0; rr < 4; ++rr) {
                float4 v = *(const float4*)&sm.s_seq[rg * 4 + rr][d4 * 4];
                sa[rr][0] = v.x; sa[rr][1] = v.y; sa[rr][2] = v.z; sa[rr][3] = v.w;
            }
            #pragma unroll
            for (int j = 0; j < 4; ++j) {
                const int d = d4 * 4 + j;
                float4 wq = *(const float4*)&Wq[d * EMB + e0];
                float4 wk = *(const float4*)&Wk[d * EMB + e0];
                #pragma unroll
                for (int rr = 0; rr < 4; ++rr) {
                    float s = sa[rr][j];
                    accq[rr][0] += s * wq.x; accq[rr][1] += s * wq.y;
                    accq[rr][2] += s * wq.z; accq[rr][3] += s * wq.w;
                    acck[rr][0] += s * wk.x; acck[rr][1] += s * wk.y;
                    acck[rr][2] += s * wk.z; acck[rr][3] += s * wk.w;
                }
            }
        }
        #pragma unroll
        for (int rr = 0; rr < 4; ++rr) {
            int row = rg * 4 + rr;
            if (row < slen_i) {
                float q0 = 1.f / (1.f + __expf(-accq[rr][0]));
                float q1 = 1.f / (1.f + __expf(-accq[rr][1]));
                float q2 = 1.f / (1.f + __expf(-accq[rr][2]));
                float q3 = 1.f / (1.f + __expf(-accq[rr][3]));
                float k0 = 1.f / (1.f + __expf(-acck[rr][0]));
                float k1 = 1.f / (1.f + __expf(-acck[rr][1]));
                float k2 = 1.f / (1.f + __expf(-acck[rr][2]));
                float k3 = 1.f / (1.f + __expf(-acck[rr][3]));
                half2_t hq0 = {(_Float16)q0, (_Float16)q1};
                half2_t hq1 = {(_Float16)q2, (_Float16)q3};
                half2_t hk0 = {(_Float16)k0, (_Float16)k1};
                half2_t hk1 = {(_Float16)k2, (_Float16)k3};
                *(half2_t*)&sm.sQ[row][e0]     = hq0;
                *(half2_t*)&sm.sQ[row][e0 + 2] = hq1;
                *(half2_t*)&sm.sK[row][e0]     = hk0;
                *(half2_t*)&sm.sK[row][e0 + 2] = hk1;
            }
        }
    }
    __syncthreads();

    // phase 3: score partials, l,m < slen (fp16 dot2, 4-way ILP)
    const float inv_sqrt_d = rsqrtf((float)EMB);
    if (t < 200) {
        const int l = t >> 2;
        const int m0 = t & 3;
        float partial = 0.f;
        if (l < slen_i) {
            const half2_t* qp = (const half2_t*)&sm.sQ[l][0];
            for (int m = m0; m < slen_i; m += 4) {
                if (m == l) continue;
                const half2_t* kp = (const half2_t*)&sm.sK[m][0];
                float d0 = 0.f, d1 = 0.f, d2 = 0.f, d3 = 0.f;
                #pragma unroll
                for (int d = 0; d < 56; d += 4) {
                    d0 = fdot2(qp[d],     kp[d],     d0);
                    d1 = fdot2(qp[d + 1], kp[d + 1], d1);
                    d2 = fdot2(qp[d + 2], kp[d + 2], d2);
                    d3 = fdot2(qp[d + 3], kp[d + 3], d3);
                }
                float dot = (d0 + d1) + (d2 + d3);
                partial += inv_sqrt_d / (1.f + __expf(-dot));
            }
        }
        sm.s_part[l][m0] = partial;
    }
    __syncthreads();

    // phase 4: masked softmax (wave 0)
    if (t < 64) {
        float slen = (float)slen_i;
        float a = -1e30f;
        if (t < slen_i)
            a = (sm.s_part[t][0] + sm.s_part[t][1] +
                 sm.s_part[t][2] + sm.s_part[t][3]) / slen;
        float mx = a;
        for (int o = 32; o > 0; o >>= 1) mx = fmaxf(mx, __shfl_xor(mx, o));
        float ex = __expf(a - mx);
        float sm_ = ex;
        for (int o = 32; o > 0; o >>= 1) sm_ += __shfl_xor(sm_, o);
        if (t < SEQL) sm.s_beta[t] = ex / sm_;
    }
    __syncthreads();

    // phase 5: pooled output (beta[l]=0 exactly for l>=slen)
    if (t < EMB) {
        float h = 0.f;
        for (int l = 0; l < slen_i; ++l) h += sm.s_beta[l] * sm.s_seq[l][t];
        seq_h[b * EMB + t] = h;
        acc2[b * EMB + t] = h;
    }
}

// ---------------- fused session layer: s_new = DA @ (s @ W^T), norm, acc ---
__global__ __launch_bounds__(128) void sess_fused(
    const float* __restrict__ DA, const float* __restrict__ s_in,
    const float* __restrict__ W,
    float* __restrict__ s_out, float* __restrict__ acc2,
    float* __restrict__ out, int is_last)
{
    __shared__ float da[BATCH];
    __shared__ float u[EMB];
    __shared__ float red[128];
    const int b = blockIdx.x;
    const int e = threadIdx.x;

    for (int k = e; k < BATCH; k += 128) da[k] = DA[b * BATCH + k];
    __syncthreads();

    float uu = 0.f;
    if (e < EMB) {
        #pragma unroll 8
        for (int k = 0; k < BATCH; ++k) uu += da[k] * s_in[k * EMB + e];
        u[e] = uu;
    }
    __syncthreads();

    float v = 0.f;
    if (e < EMB) {
        #pragma unroll 8
        for (int d = 0; d < EMB; ++d) v += u[d] * W[e * EMB + d];
    }
    red[e] = (e < EMB) ? v * v : 0.f;
    __syncthreads();
    for (int off = 64; off > 0; off >>= 1) {
        if (e < off) red[e] += red[e + off];
        __syncthreads();
    }
    float nrm = fmaxf(sqrtf(red[0]), 1e-12f);
    if (e < EMB) {
        float a = acc2[b * EMB + e] + v / nrm;
        acc2[b * EMB + e] = a;
        s_out[b * EMB + e] = v;
        if (is_last) out[b * EMB + e] = a * (1.f / 3.f);
    }
}

extern "C" void kernel_launch(void* const* d_in, const int* in_sizes, int n_in,
                              void* d_out, int out_size, void* d_ws, size_t ws_size,
                              hipStream_t stream)
{
    (void)in_sizes; (void)n_in; (void)out_size; (void)ws_size;

    const float* embedding    = (const float*)d_in[0];
    const float* adj_vals     = (const float*)d_in[1];
    const float* W_q          = (const float*)d_in[2];
    const float* W_k          = (const float*)d_in[3];
    const float* w_sess       = (const float*)d_in[4];
    const float* D            = (const float*)d_in[5];
    const float* A            = (const float*)d_in[6];
    const int*   adj_rows     = (const int*)d_in[7];
    const int*   adj_cols     = (const int*)d_in[8];
    const int*   session_item = (const int*)d_in[9];
    const int*   session_len  = (const int*)d_in[10];
    float* out = (float*)d_out;

    // ---- workspace layout ----
    unsigned short* ebf0 = (unsigned short*)d_ws;                 // 2 x 12.8M ushort
    unsigned short* ebf1 = ebf0 + (size_t)N_NODE * EMBP;
    float* DAb       = (float*)(ebf1 + (size_t)N_NODE * EMBP);    // 8B-aligned
    float* seqh      = DAb  + (size_t)BATCH * BATCH;
    float* acc2      = seqh + (size_t)BATCH * EMB;
    float* sbuf      = acc2 + (size_t)BATCH * EMB;
    int*   counts    = (int*)(sbuf + (size_t)BATCH * EMB);
    int*   row_start = counts + N_NODE;
    int*   bcur      = row_start + N_NODE;                        // NBUCK, pad 2048
    int2*  csr_cv    = (int2*)(bcur + 2048);                      // 14.4 MB
    uint2* staged    = (uint2*)(csr_cv + (size_t)NBUCK * BUCK_CAP); // 14.4 MB
    // staged is dead after bucket_csr_spmm; reuse it for the gathered seq rows
    float* seqg      = (float*)staged;                            // 11.5 MB < 14.4 MB

    hipMemsetAsync(bcur, 0, 2048 * sizeof(int), stream);

    // ---- fused: edge binning (head, LDS-grouped writes) + prep behind ----
    prep_bin<<<P1_BLOCKS + NPREP1024, 1024, 0, stream>>>(
        embedding, ebf0, adj_rows, adj_cols, adj_vals, bcur, staged);

    // ---- fused: bucket sort/csr/spmm + DA=D@A gemm (overlapped) ----
    bucket_csr_spmm<<<NBUCK + NGEMM, 1024, 0, stream>>>(
        staged, bcur, ebf0, ebf1, csr_cv, row_start, counts, D, A, DAb);

    // ---- high-occupancy layer-2 gather of all (b,l) seq rows ----
    gather_seq<<<NROWS / 8, 256, 0, stream>>>(embedding, ebf1, csr_cv,
                                              row_start, counts, session_item,
                                              seqg);

    // ---- attention (slen-capped) ----
    attn_pool<<<BATCH, 256, 0, stream>>>(seqg, W_q, W_k, session_len,
                                         seqh, acc2);

    // ---- session graph: 2 fused layers ----
    sess_fused<<<BATCH, 128, 0, stream>>>(DAb, seqh, w_sess + 0 * EMB * EMB,
                                          sbuf, acc2, out, 0);
    sess_fused<<<BATCH, 128, 0, stream>>>(DAb, sbuf, w_sess + 1 * EMB * EMB,
                                          sbuf, acc2, out, 1);
}

// Round 13
// 303.857 us; speedup vs baseline: 1.0063x; 1.0063x over previous
//
#include <hip/hip_runtime.h>

#define N_NODE 100000
#define EMB 112
#define EMBP 128                      // padded bf16 row: 256 B, line-aligned
#define BATCH 512
#define SEQL 50
#define NNZ 1600000
#define NROWS (BATCH * SEQL)

#define BROWS 256                     // rows per bucket
#define NBUCK ((N_NODE + BROWS - 1) / BROWS)      // 391
#define BUCK_CAP 4608                 // mean 4096, sd 64 -> 8 sigma headroom
#define TILE_E 6250                   // 256 bin blocks x 1024 threads, exact
#define P1_BLOCKS 256
#define NPREP1024 (N_NODE * 32 / 1024)            // 3125 prep blocks @1024 thr
#define NGEMM 64                      // 64x64-tile DA gemm blocks

typedef _Float16 half2_t __attribute__((ext_vector_type(2)));

__device__ __forceinline__ float bf2f(unsigned short u) {
    return __uint_as_float((unsigned)u << 16);
}
__device__ __forceinline__ unsigned short f2bf(float f) {
    unsigned u = __float_as_uint(f);
    return (unsigned short)((u + 0x7FFF + ((u >> 16) & 1)) >> 16);   // RNE
}
__device__ __forceinline__ float fdot2(half2_t a, half2_t b, float c) {
#if defined(__has_builtin)
#if __has_builtin(__builtin_amdgcn_fdot2)
    return __builtin_amdgcn_fdot2(a, b, c, false);
#else
    return c + (float)a[0] * (float)b[0] + (float)a[1] * (float)b[1];
#endif
#else
    return c + (float)a[0] * (float)b[0] + (float)a[1] * (float)b[1];
#endif
}

// ---- fused: edge binning (blocks [0,256), head of grid) + prep behind -----
// Bin branch: block-local counting sort in LDS so staged[] writes are
// line-coalesced. rows[] register-staged across passes (read once).
struct BinSmem {
    uint2 sdata[TILE_E];              // 50000 B, bucket-grouped edges
    unsigned short sbuck[TILE_E];     // 12500 B, bucket id per slot
    int hist[NBUCK];
    int sc[NBUCK];                    // inclusive scan
    int gbase[NBUCK];                 // global reservation base
    int cur[NBUCK];                   // local scatter cursor
};

__global__ __launch_bounds__(1024) void prep_bin(
    const float* __restrict__ in, unsigned short* __restrict__ out,
    const int* __restrict__ rows, const int* __restrict__ cols,
    const float* __restrict__ vals,
    int* __restrict__ bcur, uint2* __restrict__ staged)
{
    __shared__ BinSmem sm;
    const int t = threadIdx.x;

    if (blockIdx.x >= P1_BLOCKS) {
        // ---- prep branch: fp32 -> padded bf16 table ----
        int i = (blockIdx.x - P1_BLOCKS) * 1024 + t;
        int r = i >> 5, c = i & 31;
        ushort4 o; o.x = 0; o.y = 0; o.z = 0; o.w = 0;
        if (c < 28) {
            float4 v = ((const float4*)in)[r * 28 + c];
            o.x = f2bf(v.x); o.y = f2bf(v.y); o.z = f2bf(v.z); o.w = f2bf(v.w);
        }
        ((ushort4*)out)[i] = o;
        return;
    }

    // ---- edge_bin branch ----
    const int e0 = blockIdx.x * TILE_E;

    // A: histogram, register-staging rows (max 7 edges per thread)
    int rreg[7];
    int nume = 0;
    for (int i = t; i < NBUCK; i += 1024) sm.hist[i] = 0;
    __syncthreads();
    #pragma unroll
    for (int j = 0; j < 7; ++j) {
        int e = e0 + t + j * 1024;
        if (t + j * 1024 < TILE_E) {
            int r = rows[e];
            rreg[j] = r;
            atomicAdd(&sm.hist[r >> 8], 1);
            nume = j + 1;
        }
    }
    __syncthreads();

    // B: local exclusive scan + global reservation
    for (int i = t; i < NBUCK; i += 1024) sm.sc[i] = sm.hist[i];
    __syncthreads();
    for (int o = 1; o < NBUCK; o <<= 1) {
        int v = 0;
        if (t < NBUCK && t >= o) v = sm.sc[t - o];
        __syncthreads();
        if (t < NBUCK) sm.sc[t] += v;
        __syncthreads();
    }
    if (t < NBUCK) {
        int c = sm.hist[t];
        int excl = sm.sc[t] - c;
        sm.cur[t] = excl;
        sm.gbase[t] = (c > 0) ? atomicAdd(&bcur[t], c) : 0;
    }
    __syncthreads();

    // C: scatter edges into LDS grouped by bucket (rows from registers)
    #pragma unroll
    for (int j = 0; j < 7; ++j) {
        if (j < nume) {
            int e = e0 + t + j * 1024;
            int r = rreg[j];
            int b = r >> 8;
            int k = atomicAdd(&sm.cur[b], 1);
            uint2 s;
            s.x = ((unsigned)(r & 255) << 24) | (unsigned)cols[e];
            s.y = __float_as_uint(vals[e]);
            sm.sdata[k] = s;
            sm.sbuck[k] = (unsigned short)b;
        }
    }
    __syncthreads();

    // D: line-coalesced write-out (consecutive slots -> consecutive gdst)
    for (int i = t; i < TILE_E; i += 1024) {
        int b = sm.sbuck[i];
        int lbase = sm.sc[b] - sm.hist[b];
        staged[(size_t)b * BUCK_CAP + sm.gbase[b] + (i - lbase)] = sm.sdata[i];
    }
}

// ---- fused: bucket sort/csr/spmm (blocks [0,391)) + DA gemm ([391,455)) ---
// The gather is at the random-256B-row hardware floor (confirmed: BW
// invariant across occupancy 49-68% and flight depth 8/12). Keep the
// R11-measured-best 8-unroll body.
struct SortSmem {
    uint2 s_sorted[BUCK_CAP];
    int cnt[BROWS];
    int sc[BROWS];
    int cur[BROWS];
};
struct Gemm64Smem {
    float sD[64][33];
    float sA[32][65];
};
union BuckSmem { SortSmem s; Gemm64Smem g; };

__global__ __launch_bounds__(1024) void bucket_csr_spmm(
    const uint2* __restrict__ staged, const int* __restrict__ bcur,
    const unsigned short* __restrict__ src, unsigned short* __restrict__ dst,
    int2* __restrict__ csr_cv, int* __restrict__ row_start,
    int* __restrict__ counts,
    const float* __restrict__ D, const float* __restrict__ A,
    float* __restrict__ DA)
{
    __shared__ BuckSmem sm;
    const int t = threadIdx.x;

    if (blockIdx.x >= NBUCK) {
        // ---------------- DA = D @ A, 64x64 tile per block ----------------
        const int bid = blockIdx.x - NBUCK;
        const int i0 = (bid >> 3) * 64;
        const int j0 = (bid & 7) * 64;
        const int tx = t & 31;
        const int ty = t >> 5;
        float a00 = 0.f, a01 = 0.f, a10 = 0.f, a11 = 0.f;
        for (int k0 = 0; k0 < BATCH; k0 += 32) {
            int idx = t;
            #pragma unroll
            for (int rpt = 0; rpt < 2; ++rpt, idx += 1024) {
                int r = idx >> 5, c = idx & 31;
                sm.g.sD[r][c] = D[(i0 + r) * BATCH + k0 + c];
                int r2 = idx >> 6, c2 = idx & 63;
                sm.g.sA[r2][c2] = A[(k0 + r2) * BATCH + j0 + c2];
            }
            __syncthreads();
            #pragma unroll 8
            for (int kk = 0; kk < 32; ++kk) {
                float d0 = sm.g.sD[2 * ty][kk], d1 = sm.g.sD[2 * ty + 1][kk];
                float b0 = sm.g.sA[kk][2 * tx], b1 = sm.g.sA[kk][2 * tx + 1];
                a00 += d0 * b0; a01 += d0 * b1;
                a10 += d1 * b0; a11 += d1 * b1;
            }
            __syncthreads();
        }
        DA[(i0 + 2 * ty) * BATCH + j0 + 2 * tx] = a00;
        DA[(i0 + 2 * ty) * BATCH + j0 + 2 * tx + 1] = a01;
        DA[(i0 + 2 * ty + 1) * BATCH + j0 + 2 * tx] = a10;
        DA[(i0 + 2 * ty + 1) * BATCH + j0 + 2 * tx + 1] = a11;
        return;
    }

    // ---------------- bucket sort + csr emit + spmm layer 1 ----------------
    const int b = blockIdx.x;
    const int n = bcur[b];
    const size_t base = (size_t)b * BUCK_CAP;
    const int r0 = b << 8;

    if (t < BROWS) sm.s.cnt[t] = 0;
    __syncthreads();
    for (int i = t; i < n; i += 1024)
        atomicAdd(&sm.s.cnt[staged[base + i].x >> 24], 1);
    __syncthreads();

    if (t < BROWS) sm.s.sc[t] = sm.s.cnt[t];
    __syncthreads();
    for (int o = 1; o < BROWS; o <<= 1) {
        int v = 0;
        if (t < BROWS && t >= o) v = sm.s.sc[t - o];
        __syncthreads();
        if (t < BROWS) sm.s.sc[t] += v;
        __syncthreads();
    }
    if (t < BROWS) {
        int excl = sm.s.sc[t] - sm.s.cnt[t];
        sm.s.cur[t] = excl;
        int row = r0 + t;
        if (row < N_NODE) {
            row_start[row] = (int)base + excl;
            counts[row] = sm.s.cnt[t];
        }
    }
    __syncthreads();

    for (int i = t; i < n; i += 1024) {
        uint2 s = staged[base + i];
        int rl = s.x >> 24;
        int k = atomicAdd(&sm.s.cur[rl], 1);
        uint2 e;
        e.x = s.x & 0x00FFFFFFu;
        e.y = s.y;
        sm.s.s_sorted[k] = e;
    }
    __syncthreads();

    for (int i = t; i < n; i += 1024) {
        uint2 e = sm.s.s_sorted[i];
        int2 cv; cv.x = (int)e.x; cv.y = (int)e.y;
        csr_cv[base + i] = cv;
    }

    // spmm layer 1 for this bucket's 256 rows, edges from LDS
    const int wave = t >> 6;
    const int lane = t & 63;
    const int half = lane >> 5;
    const int hl = lane & 31;
    const int d0 = hl * 4;

    for (int it = 0; it < 8; ++it) {
        int rl = wave * 16 + it * 2 + half;
        int row = r0 + rl;
        bool valid = row < N_NODE;
        int n_r = valid ? sm.s.cnt[rl] : 0;
        int beg = valid ? (sm.s.sc[rl] - sm.s.cnt[rl]) : 0;

        float a0 = 0.f, a1 = 0.f, a2 = 0.f, a3 = 0.f;
        int i = 0;
        for (; i + 8 <= n_r; i += 8) {
            #pragma unroll
            for (int j = 0; j < 8; ++j) {
                uint2 e = sm.s.s_sorted[beg + i + j];
                float v = __uint_as_float(e.y);
                ushort4 u = *(const ushort4*)(src + (size_t)e.x * EMBP + d0);
                a0 += v * bf2f(u.x);
                a1 += v * bf2f(u.y);
                a2 += v * bf2f(u.z);
                a3 += v * bf2f(u.w);
            }
        }
        for (; i < n_r; ++i) {
            uint2 e = sm.s.s_sorted[beg + i];
            float v = __uint_as_float(e.y);
            ushort4 u = *(const ushort4*)(src + (size_t)e.x * EMBP + d0);
            a0 += v * bf2f(u.x);
            a1 += v * bf2f(u.y);
            a2 += v * bf2f(u.z);
            a3 += v * bf2f(u.w);
        }
        if (valid) {
            ushort4 o;
            o.x = f2bf(a0); o.y = f2bf(a1); o.z = f2bf(a2); o.w = f2bf(a3);
            *(ushort4*)(dst + (size_t)row * EMBP + d0) = o;
        }
    }
}

// ---- gather_seq: on-the-fly layer-2 rows for all (b,l) slots --------------
__global__ __launch_bounds__(256) void gather_seq(
    const float* __restrict__ emb0,
    const unsigned short* __restrict__ e1b,
    const int2* __restrict__ csr_cv, const int* __restrict__ row_start,
    const int* __restrict__ counts,
    const int* __restrict__ items,
    float* __restrict__ seqg)
{
    const int t = threadIdx.x;
    const int hw = t >> 5;        // 0..7 half-waves
    const int hl = t & 31;
    const int d0 = hl * 4;
    const int slot = blockIdx.x * 8 + hw;
    if (slot >= NROWS) return;

    float a0 = 0.f, a1 = 0.f, a2 = 0.f, a3 = 0.f;
    const int g = items[slot];
    if (g > 0) {
        const int r = g - 1;
        const int n = counts[r];
        const int beg = row_start[r];
        int i = 0;
        for (; i + 8 <= n; i += 8) {
            #pragma unroll
            for (int j = 0; j < 8; ++j) {
                int2 cv = csr_cv[beg + i + j];
                float v = __int_as_float(cv.y);
                ushort4 u = *(const ushort4*)(e1b + (size_t)cv.x * EMBP + d0);
                a0 += v * bf2f(u.x);
                a1 += v * bf2f(u.y);
                a2 += v * bf2f(u.z);
                a3 += v * bf2f(u.w);
            }
        }
        for (; i < n; ++i) {
            int2 cv = csr_cv[beg + i];
            float v = __int_as_float(cv.y);
            ushort4 u = *(const ushort4*)(e1b + (size_t)cv.x * EMBP + d0);
            a0 += v * bf2f(u.x);
            a1 += v * bf2f(u.y);
            a2 += v * bf2f(u.z);
            a3 += v * bf2f(u.w);
        }
        // + emb1 self + emb0 self
        ushort4 u1 = *(const ushort4*)(e1b + (size_t)r * EMBP + d0);
        a0 += bf2f(u1.x); a1 += bf2f(u1.y); a2 += bf2f(u1.z); a3 += bf2f(u1.w);
        if (hl < 28) {
            float4 v0 = *(const float4*)(emb0 + (size_t)r * EMB + d0);
            a0 += v0.x; a1 += v0.y; a2 += v0.z; a3 += v0.w;
        }
        a0 *= (1.f / 3.f); a1 *= (1.f / 3.f);
        a2 *= (1.f / 3.f); a3 *= (1.f / 3.f);
    }
    if (hl < 28) {
        float4 w; w.x = a0; w.y = a1; w.z = a2; w.w = a3;
        *(float4*)(seqg + (size_t)slot * EMB + d0) = w;
    }
}

// ---------------- attention (slen-capped), 512 pure-attn blocks ------------
// LDS ~48 KB (fp16 Q/K) -> 3 blocks/CU. mask is a contiguous prefix
// (arange(SEQ) < session_len), so capping loops at slen is bit-identical.
#define APAD 116
#define HPAD 120
struct AttnSmem {
    float s_seq[52][APAD];            // 23.6 KB
    _Float16 sQ[SEQL][HPAD];          // 11.7 KB
    _Float16 sK[SEQL][HPAD];          // 11.7 KB
    float s_part[SEQL][4];
    float s_beta[SEQL];
};

__global__ __launch_bounds__(256, 3) void attn_pool(
    const float* __restrict__ seqg,
    const float* __restrict__ Wq, const float* __restrict__ Wk,
    const int* __restrict__ session_len,
    float* __restrict__ seq_h, float* __restrict__ acc2)
{
    __shared__ AttnSmem sm;
    const int t = threadIdx.x;
    const int b = blockIdx.x;
    const int slen_i = session_len[b];            // uniform per block

    // phase 1: coalesced stage of precomputed seq rows
    for (int u = t; u < SEQL * 28; u += 256) {
        int l = u / 28;
        int q = u - l * 28;
        *(float4*)&sm.s_seq[l][q * 4] =
            *(const float4*)(seqg + (size_t)(b * SEQL + l) * EMB + q * 4);
    }
    if (t < 2 * 28) {                 // zero pad rows 50,51
        int l = SEQL + (t / 28);
        int q = t - (t / 28) * 28;
        float4 z; z.x = 0.f; z.y = 0.f; z.z = 0.f; z.w = 0.f;
        *(float4*)&sm.s_seq[l][q * 4] = z;
    }
    __syncthreads();

    // phase 2: Q/K projection, only rows < slen (rest are exact zeros
    // downstream). rgmax*28 work items, 4x4 register tiles.
    const int rgmax = (slen_i + 3) >> 2;
    for (int u = t; u < rgmax * 28; u += 256) {
        const int rg = u / 28;
        const int e0 = (u - rg * 28) * 4;
        float accq[4][4] = {{0.f}}, acck[4][4] = {{0.f}};
        #pragma unroll 2
        for (int d4 = 0; d4 < 28; ++d4) {
            float sa[4][4];
            #pragma unroll
            for (int rr = 0; rr < 4; ++rr) {
                float4 v = *(const float4*)&sm.s_seq[rg * 4 + rr][d4 * 4];
                sa[rr][0] = v.x; sa[rr][1] = v.y; sa[rr][2] = v.z; sa[rr][3] = v.w;
            }
            #pragma unroll
            for (int j = 0; j < 4; ++j) {
                const int d = d4 * 4 + j;
                float4 wq = *(const float4*)&Wq[d * EMB + e0];
                float4 wk = *(const float4*)&Wk[d * EMB + e0];
                #pragma unroll
                for (int rr = 0; rr < 4; ++rr) {
                    float s = sa[rr][j];
                    accq[rr][0] += s * wq.x; accq[rr][1] += s * wq.y;
                    accq[rr][2] += s * wq.z; accq[rr][3] += s * wq.w;
                    acck[rr][0] += s * wk.x; acck[rr][1] += s * wk.y;
                    acck[rr][2] += s * wk.z; acck[rr][3] += s * wk.w;
                }
            }
        }
        #pragma unroll
        for (int rr = 0; rr < 4; ++rr) {
            int row = rg * 4 + rr;
            if (row < slen_i) {
                float q0 = 1.f / (1.f + __expf(-accq[rr][0]));
                float q1 = 1.f / (1.f + __expf(-accq[rr][1]));
                float q2 = 1.f / (1.f + __expf(-accq[rr][2]));
                float q3 = 1.f / (1.f + __expf(-accq[rr][3]));
                float k0 = 1.f / (1.f + __expf(-acck[rr][0]));
                float k1 = 1.f / (1.f + __expf(-acck[rr][1]));
                float k2 = 1.f / (1.f + __expf(-acck[rr][2]));
                float k3 = 1.f / (1.f + __expf(-acck[rr][3]));
                half2_t hq0 = {(_Float16)q0, (_Float16)q1};
                half2_t hq1 = {(_Float16)q2, (_Float16)q3};
                half2_t hk0 = {(_Float16)k0, (_Float16)k1};
                half2_t hk1 = {(_Float16)k2, (_Float16)k3};
                *(half2_t*)&sm.sQ[row][e0]     = hq0;
                *(half2_t*)&sm.sQ[row][e0 + 2] = hq1;
                *(half2_t*)&sm.sK[row][e0]     = hk0;
                *(half2_t*)&sm.sK[row][e0 + 2] = hk1;
            }
        }
    }
    __syncthreads();

    // phase 3: score partials, l,m < slen (fp16 dot2, 4-way ILP)
    const float inv_sqrt_d = rsqrtf((float)EMB);
    if (t < 200) {
        const int l = t >> 2;
        const int m0 = t & 3;
        float partial = 0.f;
        if (l < slen_i) {
            const half2_t* qp = (const half2_t*)&sm.sQ[l][0];
            for (int m = m0; m < slen_i; m += 4) {
                if (m == l) continue;
                const half2_t* kp = (const half2_t*)&sm.sK[m][0];
                float d0 = 0.f, d1 = 0.f, d2 = 0.f, d3 = 0.f;
                #pragma unroll
                for (int d = 0; d < 56; d += 4) {
                    d0 = fdot2(qp[d],     kp[d],     d0);
                    d1 = fdot2(qp[d + 1], kp[d + 1], d1);
                    d2 = fdot2(qp[d + 2], kp[d + 2], d2);
                    d3 = fdot2(qp[d + 3], kp[d + 3], d3);
                }
                float dot = (d0 + d1) + (d2 + d3);
                partial += inv_sqrt_d / (1.f + __expf(-dot));
            }
        }
        sm.s_part[l][m0] = partial;
    }
    __syncthreads();

    // phase 4: masked softmax (wave 0)
    if (t < 64) {
        float slen = (float)slen_i;
        float a = -1e30f;
        if (t < slen_i)
            a = (sm.s_part[t][0] + sm.s_part[t][1] +
                 sm.s_part[t][2] + sm.s_part[t][3]) / slen;
        float mx = a;
        for (int o = 32; o > 0; o >>= 1) mx = fmaxf(mx, __shfl_xor(mx, o));
        float ex = __expf(a - mx);
        float sm_ = ex;
        for (int o = 32; o > 0; o >>= 1) sm_ += __shfl_xor(sm_, o);
        if (t < SEQL) sm.s_beta[t] = ex / sm_;
    }
    __syncthreads();

    // phase 5: pooled output (beta[l]=0 exactly for l>=slen)
    if (t < EMB) {
        float h = 0.f;
        for (int l = 0; l < slen_i; ++l) h += sm.s_beta[l] * sm.s_seq[l][t];
        seq_h[b * EMB + t] = h;
        acc2[b * EMB + t] = h;
    }
}

// ---------------- fused session layer: s_new = DA @ (s @ W^T), norm, acc ---
__global__ __launch_bounds__(128) void sess_fused(
    const float* __restrict__ DA, const float* __restrict__ s_in,
    const float* __restrict__ W,
    float* __restrict__ s_out, float* __restrict__ acc2,
    float* __restrict__ out, int is_last)
{
    __shared__ float da[BATCH];
    __shared__ float u[EMB];
    __shared__ float red[128];
    const int b = blockIdx.x;
    const int e = threadIdx.x;

    for (int k = e; k < BATCH; k += 128) da[k] = DA[b * BATCH + k];
    __syncthreads();

    float uu = 0.f;
    if (e < EMB) {
        #pragma unroll 8
        for (int k = 0; k < BATCH; ++k) uu += da[k] * s_in[k * EMB + e];
        u[e] = uu;
    }
    __syncthreads();

    float v = 0.f;
    if (e < EMB) {
        #pragma unroll 8
        for (int d = 0; d < EMB; ++d) v += u[d] * W[e * EMB + d];
    }
    red[e] = (e < EMB) ? v * v : 0.f;
    __syncthreads();
    for (int off = 64; off > 0; off >>= 1) {
        if (e < off) red[e] += red[e + off];
        __syncthreads();
    }
    float nrm = fmaxf(sqrtf(red[0]), 1e-12f);
    if (e < EMB) {
        float a = acc2[b * EMB + e] + v / nrm;
        acc2[b * EMB + e] = a;
        s_out[b * EMB + e] = v;
        if (is_last) out[b * EMB + e] = a * (1.f / 3.f);
    }
}

extern "C" void kernel_launch(void* const* d_in, const int* in_sizes, int n_in,
                              void* d_out, int out_size, void* d_ws, size_t ws_size,
                              hipStream_t stream)
{
    (void)in_sizes; (void)n_in; (void)out_size; (void)ws_size;

    const float* embedding    = (const float*)d_in[0];
    const float* adj_vals     = (const float*)d_in[1];
    const float* W_q          = (const float*)d_in[2];
    const float* W_k          = (const float*)d_in[3];
    const float* w_sess       = (const float*)d_in[4];
    const float* D            = (const float*)d_in[5];
    const float* A            = (const float*)d_in[6];
    const int*   adj_rows     = (const int*)d_in[7];
    const int*   adj_cols     = (const int*)d_in[8];
    const int*   session_item = (const int*)d_in[9];
    const int*   session_len  = (const int*)d_in[10];
    float* out = (float*)d_out;

    // ---- workspace layout ----
    unsigned short* ebf0 = (unsigned short*)d_ws;                 // 2 x 12.8M ushort
    unsigned short* ebf1 = ebf0 + (size_t)N_NODE * EMBP;
    float* DAb       = (float*)(ebf1 + (size_t)N_NODE * EMBP);    // 8B-aligned
    float* seqh      = DAb  + (size_t)BATCH * BATCH;
    float* acc2      = seqh + (size_t)BATCH * EMB;
    float* sbuf      = acc2 + (size_t)BATCH * EMB;
    int*   counts    = (int*)(sbuf + (size_t)BATCH * EMB);
    int*   row_start = counts + N_NODE;
    int*   bcur      = row_start + N_NODE;                        // NBUCK, pad 2048
    int2*  csr_cv    = (int2*)(bcur + 2048);                      // 14.4 MB
    uint2* staged    = (uint2*)(csr_cv + (size_t)NBUCK * BUCK_CAP); // 14.4 MB
    // staged is dead after bucket_csr_spmm; reuse it for the gathered seq rows
    float* seqg      = (float*)staged;                            // 11.5 MB < 14.4 MB

    hipMemsetAsync(bcur, 0, 2048 * sizeof(int), stream);

    // ---- fused: edge binning (head, LDS-grouped writes) + prep behind ----
    prep_bin<<<P1_BLOCKS + NPREP1024, 1024, 0, stream>>>(
        embedding, ebf0, adj_rows, adj_cols, adj_vals, bcur, staged);

    // ---- fused: bucket sort/csr/spmm + DA=D@A gemm (overlapped) ----
    bucket_csr_spmm<<<NBUCK + NGEMM, 1024, 0, stream>>>(
        staged, bcur, ebf0, ebf1, csr_cv, row_start, counts, D, A, DAb);

    // ---- high-occupancy layer-2 gather of all (b,l) seq rows ----
    gather_seq<<<NROWS / 8, 256, 0, stream>>>(embedding, ebf1, csr_cv,
                                              row_start, counts, session_item,
                                              seqg);

    // ---- attention (slen-capped) ----
    attn_pool<<<BATCH, 256, 0, stream>>>(seqg, W_q, W_k, session_len,
                                         seqh, acc2);

    // ---- session graph: 2 fused layers ----
    sess_fused<<<BATCH, 128, 0, stream>>>(DAb, seqh, w_sess + 0 * EMB * EMB,
                                          sbuf, acc2, out, 0);
    sess_fused<<<BATCH, 128, 0, stream>>>(DAb, sbuf, w_sess + 1 * EMB * EMB,
                                          sbuf, acc2, out, 1);
}